// Round 7
// baseline (236.355 us; speedup 1.0000x reference)
//
#include <hip/hip_runtime.h>
#include <math.h>

// Problem constants (match reference setup_inputs)
#define NC      80
#define A_TOT   8400
#define B_TOT   32
#define BA      (B_TOT * A_TOT)    // 268800 anchors
#define NFLAT4  (BA * 20)          // 5,376,000 float4 in (BA,80)
#define NCHUNK  (BA / 64)          // 4200 fg-scan chunks of 64 anchors
#define BLOCK   256
#define NB_FG_MAX    1050          // 4200 waves -> 1 chunk per wave
#define NB_DENSE_MAX 2100          // 8400 waves -> 640 float4 (10 KB) per wave

__device__ __forceinline__ float wave_sum(float v) {
    #pragma unroll
    for (int off = 32; off > 0; off >>= 1) v += __shfl_down(v, off, 64);
    return v;
}

// Background focal term (tv == 0): 0.75 * softplus(x) * sigmoid(x)^1.5
// MUST be the same expression in dense and fg (fg subtracts it as correction).
__device__ __forceinline__ float cls_bg_term(float x) {
    float e   = __expf(-fabsf(x));
    float ope = 1.0f + e;
    float lp  = __logf(ope);                 // log1p(e)
    float sp  = fmaxf(x, 0.0f) + lp;         // softplus(x)
    float r   = __builtin_amdgcn_rcpf(ope);
    float p   = (x >= 0.0f) ? r : (1.0f - r);   // sigmoid(x)
    return 0.75f * sp * (p * __builtin_amdgcn_sqrtf(p));
}

// ===================== dense: pure stream of pred_scores =====================
__global__ __launch_bounds__(BLOCK, 2) void loss_dense(
    const float* __restrict__ pred_scores,    // (B,A,80) flat
    float* __restrict__ partials, int nbtot, int nb1, int nb2)
{
    __shared__ float red[4];
    const int tid  = threadIdx.x;
    const int lane = tid & 63;
    const int wid  = tid >> 6;
    const float4* ps4 = (const float4*)pred_scores;

    float cls = 0.0f;
    const int nw = nb2 * 4;
    for (int base0 = ((int)blockIdx.x * 4 + wid) * 640; base0 < NFLAT4;
         base0 += nw * 640) {
        int idx = base0 + lane;
        float4 a0 = ps4[idx];
        float4 a1 = ps4[idx + 64];
        #pragma unroll
        for (int i = 0; i < 5; ++i) {
            float4 b0, b1;
            if (i < 4) { b0 = ps4[idx + 128]; b1 = ps4[idx + 192]; }
            else       { b0 = a0;             b1 = a1;             }
            cls += cls_bg_term(a0.x); cls += cls_bg_term(a0.y);
            cls += cls_bg_term(a0.z); cls += cls_bg_term(a0.w);
            cls += cls_bg_term(a1.x); cls += cls_bg_term(a1.y);
            cls += cls_bg_term(a1.z); cls += cls_bg_term(a1.w);
            a0 = b0; a1 = b1; idx += 128;
        }
    }

    float v = wave_sum(cls);
    if (lane == 0) red[wid] = v;
    __syncthreads();
    if (tid == 0) {
        float r1 = red[0] + red[1] + red[2] + red[3];
        int slot = nb1 + (int)blockIdx.x;
        partials[0 * nbtot + slot] = 0.0f;
        partials[1 * nbtot + slot] = r1;
        partials[2 * nbtot + slot] = 0.0f;
        partials[3 * nbtot + slot] = 0.0f;
    }
}

// ===================== fg: scan fgmask, full per-anchor work =====================
__global__ __launch_bounds__(BLOCK) void loss_fg(
    const float* __restrict__ pred_dist,      // (B,A,64)
    const float* __restrict__ pred_scores,    // (B,A,80)
    const float* __restrict__ anchor_points,  // (A,2)
    const float* __restrict__ target_bboxes,  // (B,A,4)
    const float* __restrict__ target_scores,  // (B,A,80)
    const int* __restrict__ fgmask,           // (B,A) bool as int32
    float* __restrict__ partials, int nbtot, int nb1)
{
    __shared__ float red[4][4];
    const int tid  = threadIdx.x;
    const int lane = tid & 63;
    const int wid  = tid >> 6;

    const float4* ps4 = (const float4*)pred_scores;
    const float4* ts4 = (const float4*)target_scores;
    const float4* tb4 = (const float4*)target_bboxes;

    float cls_acc = 0.0f, iou_acc = 0.0f, dfl_acc = 0.0f, ts_acc = 0.0f;

    const int fstride = nb1 * 4;
    for (int c = blockIdx.x * 4 + wid; c < NCHUNK; c += fstride) {
        const int abase = c * 64;
        const int myfg = fgmask[abase + lane];
        unsigned long long m = __ballot(myfg != 0);

        int gc = -1; float xc = 0.0f;
        float4 tbc = make_float4(0,0,0,0), tsc = make_float4(0,0,0,0);
        float4 psc = make_float4(0,0,0,0);
        if (m) {
            int b = __ffsll((long long)m) - 1; m &= m - 1;
            gc = abase + b;
            xc  = pred_dist[gc * 64 + lane];
            tbc = tb4[gc];
            tsc = (lane < 20) ? ts4[gc * 20 + lane] : make_float4(0,0,0,0);
            psc = (lane >= 32 && lane < 52) ? ps4[gc * 20 + (lane - 32)]
                                            : make_float4(0,0,0,0);
        }
        while (gc >= 0) {
            int gn = -1; float xn = 0.0f;
            float4 tbn = make_float4(0,0,0,0), tsn = make_float4(0,0,0,0);
            float4 psn = make_float4(0,0,0,0);
            if (m) {
                int b = __ffsll((long long)m) - 1; m &= m - 1;
                gn = abase + b;
                xn  = pred_dist[gn * 64 + lane];
                tbn = tb4[gn];
                tsn = (lane < 20) ? ts4[gn * 20 + lane] : make_float4(0,0,0,0);
                psn = (lane >= 32 && lane < 52) ? ps4[gn * 20 + (lane - 32)]
                                                : make_float4(0,0,0,0);
            }

            // bbox weight = sum of target_scores row (lanes>=20 hold 0)
            float w = tsc.x + tsc.y + tsc.z + tsc.w;
            #pragma unroll
            for (int off = 1; off < 64; off <<= 1) w += __shfl_xor(w, off, 64);

            // ---- cls correction: (full focal - bg focal) on the 80 classes ----
            // ps quad for classes [4L,4L+4) lives on lane L+32; pull to lane L.
            float qx = __shfl(psc.x, lane + 32);
            float qy = __shfl(psc.y, lane + 32);
            float qz = __shfl(psc.z, lane + 32);
            float qw = __shfl(psc.w, lane + 32);
            if (lane < 20) {
                float pxs[4] = {qx, qy, qz, qw};
                float tvs[4] = {tsc.x, tsc.y, tsc.z, tsc.w};
                #pragma unroll
                for (int j = 0; j < 4; ++j) {
                    float x  = pxs[j];
                    float tv = tvs[j];
                    float e   = __expf(-fabsf(x));
                    float ope = 1.0f + e;
                    float lp  = __logf(ope);
                    float sp  = fmaxf(x, 0.0f) + lp;          // softplus(x)
                    float r   = __builtin_amdgcn_rcpf(ope);
                    float p   = (x >= 0.0f) ? r : (1.0f - r); // sigmoid
                    float bce = sp - tv * x;
                    float u   = fmaxf(fmaf(p, 1.0f - 2.0f * tv, tv), 0.0f);
                    float af  = 0.75f - 0.5f * tv;
                    float t1  = af * bce * (u * __builtin_amdgcn_sqrtf(u));
                    float t0  = 0.75f * sp * (p * __builtin_amdgcn_sqrtf(p));
                    cls_acc += t1 - t0;
                }
            }

            const int a = gc % A_TOT;
            const float ax = anchor_points[2 * a];
            const float ay = anchor_points[2 * a + 1];
            const int side = lane >> 4;     // 0..3 = l,t,r,b
            const int k    = lane & 15;     // bin
            const float x  = xc;

            float tval = (side == 0) ? ax - tbc.x :
                         (side == 1) ? ay - tbc.y :
                         (side == 2) ? tbc.z - ax : tbc.w - ay;
            float tcl = fminf(fmaxf(tval, 0.0f), 14.99f);
            int   tl  = (int)tcl;
            float wl  = (float)(tl + 1) - tcl;
            float wr  = 1.0f - wl;

            // segmented (16-lane) softmax reductions
            float mx = x;
            mx = fmaxf(mx, __shfl_xor(mx, 1));
            mx = fmaxf(mx, __shfl_xor(mx, 2));
            mx = fmaxf(mx, __shfl_xor(mx, 4));
            mx = fmaxf(mx, __shfl_xor(mx, 8));

            float ex = __expf(x - mx);
            float se = ex;
            float nu = (float)k * ex;
            float ls = ((k == tl) ? wl : (k == tl + 1) ? wr : 0.0f) * x;
            #pragma unroll
            for (int off = 1; off < 16; off <<= 1) {
                se += __shfl_xor(se, off);
                nu += __shfl_xor(nu, off);
                ls += __shfl_xor(ls, off);
            }
            float dist = nu * __builtin_amdgcn_rcpf(se);
            float ce   = mx + __logf(se) - ls;

            float d0 = __shfl(dist, 0),  d1 = __shfl(dist, 16);
            float d2 = __shfl(dist, 32), d3 = __shfl(dist, 48);
            float c0 = __shfl(ce, 0),    c1 = __shfl(ce, 16);
            float c2 = __shfl(ce, 32),   c3 = __shfl(ce, 48);

            if (lane == 0) {
                ts_acc  += w;
                dfl_acc += 0.25f * (c0 + c1 + c2 + c3) * w;

                const float eps = 1e-7f;
                float px1 = ax - d0, py1 = ay - d1;
                float px2 = ax + d2, py2 = ay + d3;
                float w1 = px2 - px1, h1 = py2 - py1 + eps;
                float w2 = tbc.z - tbc.x, h2 = tbc.w - tbc.y + eps;
                float iw = fmaxf(fminf(px2, tbc.z) - fmaxf(px1, tbc.x), 0.0f);
                float ih = fmaxf(fminf(py2, tbc.w) - fmaxf(py1, tbc.y), 0.0f);
                float inter = iw * ih;
                float uni = w1 * h1 + w2 * h2 - inter + eps;
                float iou = inter / uni;
                float cw = fmaxf(px2, tbc.z) - fminf(px1, tbc.x);
                float ch = fmaxf(py2, tbc.w) - fminf(py1, tbc.y);
                float c2d = cw * cw + ch * ch + eps;
                float dx = tbc.x + tbc.z - px1 - px2;
                float dy = tbc.y + tbc.w - py1 - py2;
                float rho2 = (dx * dx + dy * dy) * 0.25f;
                const float c4pi2 = 0.40528473456935109f;  // 4/pi^2
                float dat = atanf(w2 / h2) - atanf(w1 / h1);
                float v = c4pi2 * dat * dat;
                float alpha = v / (v - iou + (1.0f + eps));
                float ciou = iou - (rho2 / c2d + v * alpha);
                iou_acc += (1.0f - ciou) * w;
            }

            gc = gn; xc = xn; tbc = tbn; tsc = tsn; psc = psn;
        }
    }

    float v0 = wave_sum(iou_acc);
    float v1 = wave_sum(cls_acc);
    float v2 = wave_sum(ts_acc);
    float v3 = wave_sum(dfl_acc);
    if (lane == 0) { red[0][wid] = v0; red[1][wid] = v1; red[2][wid] = v2; red[3][wid] = v3; }
    __syncthreads();
    if (tid == 0) {
        float r0 = 0, r1 = 0, r2 = 0, r3 = 0;
        #pragma unroll
        for (int i = 0; i < 4; ++i) { r0 += red[0][i]; r1 += red[1][i]; r2 += red[2][i]; r3 += red[3][i]; }
        partials[0 * nbtot + blockIdx.x] = r0;
        partials[1 * nbtot + blockIdx.x] = r1;
        partials[2 * nbtot + blockIdx.x] = r2;
        partials[3 * nbtot + blockIdx.x] = r3;
    }
}

__global__ __launch_bounds__(BLOCK) void loss_reduce(
    const float* __restrict__ partials, int nbtot, float* __restrict__ out)
{
    __shared__ float red[4][4];
    int tid = threadIdx.x;
    float s0 = 0, s1 = 0, s2 = 0, s3 = 0;
    for (int i = tid; i < nbtot; i += BLOCK) {
        s0 += partials[i];
        s1 += partials[nbtot + i];
        s2 += partials[2 * nbtot + i];
        s3 += partials[3 * nbtot + i];
    }
    s0 = wave_sum(s0); s1 = wave_sum(s1); s2 = wave_sum(s2); s3 = wave_sum(s3);
    int wid = tid >> 6;
    if ((tid & 63) == 0) { red[0][wid] = s0; red[1][wid] = s1; red[2][wid] = s2; red[3][wid] = s3; }
    __syncthreads();
    if (tid == 0) {
        float r0 = 0, r1 = 0, r2 = 0, r3 = 0;
        #pragma unroll
        for (int i = 0; i < 4; ++i) { r0 += red[0][i]; r1 += red[1][i]; r2 += red[2][i]; r3 += red[3][i]; }
        float tss = fmaxf(r2, 1.0f);
        out[0] = 7.5f * r0 / tss;   // box
        out[1] = 0.5f * r1 / tss;   // cls
        out[2] = 1.5f * r3 / tss;   // dfl
    }
}

extern "C" void kernel_launch(void* const* d_in, const int* in_sizes, int n_in,
                              void* d_out, int out_size, void* d_ws, size_t ws_size,
                              hipStream_t stream) {
    const float* pred_dist     = (const float*)d_in[0];
    const float* pred_scores   = (const float*)d_in[1];
    const float* anchor_points = (const float*)d_in[2];
    const float* target_bboxes = (const float*)d_in[3];
    const float* target_scores = (const float*)d_in[4];
    const int*   fgmask        = (const int*)d_in[5];

    int cap = (int)(ws_size / (4 * sizeof(float)));
    int nb1 = NB_FG_MAX, nb2 = NB_DENSE_MAX;
    if (nb1 + nb2 > cap) {              // scale down if workspace is tight
        nb1 = cap / 3; if (nb1 < 1) nb1 = 1;
        nb2 = cap - nb1; if (nb2 < 1) nb2 = 1;
    }
    int nbtot = nb1 + nb2;

    float* partials = (float*)d_ws;   // fully overwritten each launch
    loss_fg<<<nb1, BLOCK, 0, stream>>>(
        pred_dist, pred_scores, anchor_points, target_bboxes, target_scores,
        fgmask, partials, nbtot, nb1);
    loss_dense<<<nb2, BLOCK, 0, stream>>>(pred_scores, partials, nbtot, nb1, nb2);
    loss_reduce<<<1, BLOCK, 0, stream>>>(partials, nbtot, (float*)d_out);
}

// Round 8
// 218.658 us; speedup vs baseline: 1.0809x; 1.0809x over previous
//
#include <hip/hip_runtime.h>
#include <math.h>

// Problem constants (match reference setup_inputs)
#define NC      80
#define A_TOT   8400
#define B_TOT   32
#define BA      (B_TOT * A_TOT)    // 268800 anchors
#define NFLAT4  (BA * 20)          // 5,376,000 float4 in (B,A,80)
#define TILE4   128                // float4 per dense tile = 2 KB
#define NTILES  (NFLAT4 / TILE4)   // 42,000
#define NCHUNK  (BA / 64)          // 4200 fg-scan chunks of 64 anchors
#define BLOCK   256
#define NB_TARGET 2100             // 1050 fg blocks (1 chunk/wave) + 1050 dense blocks

__device__ __forceinline__ float wave_sum(float v) {
    #pragma unroll
    for (int off = 32; off > 0; off >>= 1) v += __shfl_down(v, off, 64);
    return v;
}

// Background focal term (tv == 0): 0.75 * softplus(x) * sigmoid(x)^1.5
// MUST be the same expression in dense and fg (fg subtracts it as correction).
__device__ __forceinline__ float cls_bg_term(float x) {
    float e   = __expf(-fabsf(x));
    float ope = 1.0f + e;
    float lp  = __logf(ope);                 // log1p(e)
    float sp  = fmaxf(x, 0.0f) + lp;         // softplus(x)
    float r   = __builtin_amdgcn_rcpf(ope);
    float p   = (x >= 0.0f) ? r : (1.0f - r);   // sigmoid(x)
    return 0.75f * sp * (p * __builtin_amdgcn_sqrtf(p));
}

// async 1 KB global->LDS (16 B/lane x 64 lanes); LDS dest is wave-uniform base
__device__ __forceinline__ void gl_lds_1k(const float4* g, float4* l) {
    __builtin_amdgcn_global_load_lds(
        (const __attribute__((address_space(1))) void*)g,
        (__attribute__((address_space(3))) void*)l, 16, 0, 0);
}

__global__ __launch_bounds__(BLOCK) void loss_main(
    const float* __restrict__ pred_dist,      // (B,A,64)
    const float* __restrict__ pred_scores,    // (B,A,80)
    const float* __restrict__ anchor_points,  // (A,2)
    const float* __restrict__ target_bboxes,  // (B,A,4)
    const float* __restrict__ target_scores,  // (B,A,80)
    const int* __restrict__ fgmask,           // (B,A) bool as int32
    float* __restrict__ partials,             // (4, nb)
    int nb, int fgb)
{
    __shared__ float4 stage[4][2][TILE4];     // 16 KB async staging (dense role)
    __shared__ float red[4][4];

    const int tid  = threadIdx.x;
    const int lane = tid & 63;
    const int wid  = tid >> 6;

    const float4* ps4 = (const float4*)pred_scores;
    const float4* ts4 = (const float4*)target_scores;
    const float4* tb4 = (const float4*)target_bboxes;

    float cls_acc = 0.0f, iou_acc = 0.0f, dfl_acc = 0.0f, ts_acc = 0.0f;

    if ((int)blockIdx.x < fgb) {
        // ===== FG role: scan fgmask; per fg anchor: cls correction + IoU + DFL =====
        const int fstride = fgb * 4;
        for (int c = blockIdx.x * 4 + wid; c < NCHUNK; c += fstride) {
            const int abase = c * 64;
            const int myfg = fgmask[abase + lane];
            unsigned long long m = __ballot(myfg != 0);

            int gc = -1; float xc = 0.0f;
            float4 tbc = make_float4(0,0,0,0), tsc = make_float4(0,0,0,0);
            float4 psc = make_float4(0,0,0,0);
            if (m) {
                int b = __ffsll((long long)m) - 1; m &= m - 1;
                gc = abase + b;
                xc  = pred_dist[gc * 64 + lane];
                tbc = tb4[gc];
                tsc = (lane < 20) ? ts4[gc * 20 + lane] : make_float4(0,0,0,0);
                psc = (lane >= 32 && lane < 52) ? ps4[gc * 20 + (lane - 32)]
                                                : make_float4(0,0,0,0);
            }
            while (gc >= 0) {
                int gn = -1; float xn = 0.0f;
                float4 tbn = make_float4(0,0,0,0), tsn = make_float4(0,0,0,0);
                float4 psn = make_float4(0,0,0,0);
                if (m) {
                    int b = __ffsll((long long)m) - 1; m &= m - 1;
                    gn = abase + b;
                    xn  = pred_dist[gn * 64 + lane];
                    tbn = tb4[gn];
                    tsn = (lane < 20) ? ts4[gn * 20 + lane] : make_float4(0,0,0,0);
                    psn = (lane >= 32 && lane < 52) ? ps4[gn * 20 + (lane - 32)]
                                                    : make_float4(0,0,0,0);
                }

                // bbox weight = sum of target_scores row (lanes>=20 hold 0)
                float w = tsc.x + tsc.y + tsc.z + tsc.w;
                #pragma unroll
                for (int off = 1; off < 64; off <<= 1) w += __shfl_xor(w, off, 64);

                // ---- cls correction: (full focal - bg focal) on the 80 classes ----
                float qx = __shfl(psc.x, lane + 32);
                float qy = __shfl(psc.y, lane + 32);
                float qz = __shfl(psc.z, lane + 32);
                float qw = __shfl(psc.w, lane + 32);
                if (lane < 20) {
                    float pxs[4] = {qx, qy, qz, qw};
                    float tvs[4] = {tsc.x, tsc.y, tsc.z, tsc.w};
                    #pragma unroll
                    for (int j = 0; j < 4; ++j) {
                        float x  = pxs[j];
                        float tv = tvs[j];
                        float e   = __expf(-fabsf(x));
                        float ope = 1.0f + e;
                        float lp  = __logf(ope);
                        float sp  = fmaxf(x, 0.0f) + lp;          // softplus(x)
                        float r   = __builtin_amdgcn_rcpf(ope);
                        float p   = (x >= 0.0f) ? r : (1.0f - r); // sigmoid
                        float bce = sp - tv * x;
                        float u   = fmaxf(fmaf(p, 1.0f - 2.0f * tv, tv), 0.0f);
                        float af  = 0.75f - 0.5f * tv;
                        float t1  = af * bce * (u * __builtin_amdgcn_sqrtf(u));
                        float t0  = 0.75f * sp * (p * __builtin_amdgcn_sqrtf(p));
                        cls_acc += t1 - t0;
                    }
                }

                const int a = gc % A_TOT;
                const float ax = anchor_points[2 * a];
                const float ay = anchor_points[2 * a + 1];
                const int side = lane >> 4;     // 0..3 = l,t,r,b
                const int k    = lane & 15;     // bin
                const float x  = xc;

                float tval = (side == 0) ? ax - tbc.x :
                             (side == 1) ? ay - tbc.y :
                             (side == 2) ? tbc.z - ax : tbc.w - ay;
                float tcl = fminf(fmaxf(tval, 0.0f), 14.99f);
                int   tl  = (int)tcl;
                float wl  = (float)(tl + 1) - tcl;
                float wr  = 1.0f - wl;

                // segmented (16-lane) softmax reductions
                float mx = x;
                mx = fmaxf(mx, __shfl_xor(mx, 1));
                mx = fmaxf(mx, __shfl_xor(mx, 2));
                mx = fmaxf(mx, __shfl_xor(mx, 4));
                mx = fmaxf(mx, __shfl_xor(mx, 8));

                float ex = __expf(x - mx);
                float se = ex;
                float nu = (float)k * ex;
                float ls = ((k == tl) ? wl : (k == tl + 1) ? wr : 0.0f) * x;
                #pragma unroll
                for (int off = 1; off < 16; off <<= 1) {
                    se += __shfl_xor(se, off);
                    nu += __shfl_xor(nu, off);
                    ls += __shfl_xor(ls, off);
                }
                float dist = nu * __builtin_amdgcn_rcpf(se);
                float ce   = mx + __logf(se) - ls;

                float d0 = __shfl(dist, 0),  d1 = __shfl(dist, 16);
                float d2 = __shfl(dist, 32), d3 = __shfl(dist, 48);
                float c0 = __shfl(ce, 0),    c1 = __shfl(ce, 16);
                float c2 = __shfl(ce, 32),   c3 = __shfl(ce, 48);

                if (lane == 0) {
                    ts_acc  += w;
                    dfl_acc += 0.25f * (c0 + c1 + c2 + c3) * w;

                    const float eps = 1e-7f;
                    float px1 = ax - d0, py1 = ay - d1;
                    float px2 = ax + d2, py2 = ay + d3;
                    float w1 = px2 - px1, h1 = py2 - py1 + eps;
                    float w2 = tbc.z - tbc.x, h2 = tbc.w - tbc.y + eps;
                    float iw = fmaxf(fminf(px2, tbc.z) - fmaxf(px1, tbc.x), 0.0f);
                    float ih = fmaxf(fminf(py2, tbc.w) - fmaxf(py1, tbc.y), 0.0f);
                    float inter = iw * ih;
                    float uni = w1 * h1 + w2 * h2 - inter + eps;
                    float iou = inter / uni;
                    float cw = fmaxf(px2, tbc.z) - fminf(px1, tbc.x);
                    float ch = fmaxf(py2, tbc.w) - fminf(py1, tbc.y);
                    float c2d = cw * cw + ch * ch + eps;
                    float dx = tbc.x + tbc.z - px1 - px2;
                    float dy = tbc.y + tbc.w - py1 - py2;
                    float rho2 = (dx * dx + dy * dy) * 0.25f;
                    const float c4pi2 = 0.40528473456935109f;  // 4/pi^2
                    float dat = atanf(w2 / h2) - atanf(w1 / h1);
                    float v = c4pi2 * dat * dat;
                    float alpha = v / (v - iou + (1.0f + eps));
                    float ciou = iou - (rho2 / c2d + v * alpha);
                    iou_acc += (1.0f - ciou) * w;
                }

                gc = gn; xc = xn; tbc = tbn; tsc = tsn; psc = psn;
            }
        }
    } else {
        // ===== Dense role: async global_load_lds double-buffered bg-focal stream =====
        // Loads consume ZERO VGPRs and cannot be sunk by the compiler; per-wave
        // in-flight pinned at 4 KB via vmcnt(2). Pure stream of pred_scores.
        const int dwid = (blockIdx.x - fgb) * 4 + wid;
        const int ndw  = (nb - fgb) * 4;
        if (dwid < NTILES) {
            float4* buf0 = stage[wid][0];
            float4* buf1 = stage[wid][1];
            const int nt = (NTILES - 1 - dwid) / ndw + 1;

            const float4* s0 = ps4 + (size_t)dwid * TILE4;
            gl_lds_1k(s0 + lane, buf0);
            gl_lds_1k(s0 + 64 + lane, buf0 + 64);
            const float4* s1 = (nt > 1) ? ps4 + (size_t)(dwid + ndw) * TILE4 : s0;
            gl_lds_1k(s1 + lane, buf1);
            gl_lds_1k(s1 + 64 + lane, buf1 + 64);

            for (int t = 0; t < nt; ++t) {
                asm volatile("s_waitcnt vmcnt(2)" ::: "memory");
                __builtin_amdgcn_sched_barrier(0);
                float4* cur = (t & 1) ? buf1 : buf0;
                float4 v0 = cur[lane];
                float4 v1 = cur[lane + 64];
                asm volatile("s_waitcnt lgkmcnt(0)" ::: "memory");
                __builtin_amdgcn_sched_barrier(0);
                // issue tile t+2 into the buffer we just consumed
                int nx = (t + 2 < nt) ? (t + 2) : (nt - 1);
                const float4* sn = ps4 + (size_t)(dwid + (size_t)nx * ndw) * TILE4;
                gl_lds_1k(sn + lane, cur);
                gl_lds_1k(sn + 64 + lane, cur + 64);
                // compute 8 bg focal terms
                cls_acc += cls_bg_term(v0.x); cls_acc += cls_bg_term(v0.y);
                cls_acc += cls_bg_term(v0.z); cls_acc += cls_bg_term(v0.w);
                cls_acc += cls_bg_term(v1.x); cls_acc += cls_bg_term(v1.y);
                cls_acc += cls_bg_term(v1.z); cls_acc += cls_bg_term(v1.w);
            }
        }
    }

    // ---- block reduce 4 scalars, write own partial slot (no atomics) ----
    float v0 = wave_sum(iou_acc);
    float v1 = wave_sum(cls_acc);
    float v2 = wave_sum(ts_acc);
    float v3 = wave_sum(dfl_acc);
    if (lane == 0) { red[0][wid] = v0; red[1][wid] = v1; red[2][wid] = v2; red[3][wid] = v3; }
    __syncthreads();
    if (tid == 0) {
        float r0 = 0, r1 = 0, r2 = 0, r3 = 0;
        #pragma unroll
        for (int i = 0; i < 4; ++i) { r0 += red[0][i]; r1 += red[1][i]; r2 += red[2][i]; r3 += red[3][i]; }
        partials[0 * nb + blockIdx.x] = r0;
        partials[1 * nb + blockIdx.x] = r1;
        partials[2 * nb + blockIdx.x] = r2;
        partials[3 * nb + blockIdx.x] = r3;
    }
}

__global__ __launch_bounds__(BLOCK) void loss_reduce(
    const float* __restrict__ partials, int nb, float* __restrict__ out)
{
    __shared__ float red[4][4];
    int tid = threadIdx.x;
    float s0 = 0, s1 = 0, s2 = 0, s3 = 0;
    for (int i = tid; i < nb; i += BLOCK) {
        s0 += partials[i];
        s1 += partials[nb + i];
        s2 += partials[2 * nb + i];
        s3 += partials[3 * nb + i];
    }
    s0 = wave_sum(s0); s1 = wave_sum(s1); s2 = wave_sum(s2); s3 = wave_sum(s3);
    int wid = tid >> 6;
    if ((tid & 63) == 0) { red[0][wid] = s0; red[1][wid] = s1; red[2][wid] = s2; red[3][wid] = s3; }
    __syncthreads();
    if (tid == 0) {
        float r0 = 0, r1 = 0, r2 = 0, r3 = 0;
        #pragma unroll
        for (int i = 0; i < 4; ++i) { r0 += red[0][i]; r1 += red[1][i]; r2 += red[2][i]; r3 += red[3][i]; }
        float tss = fmaxf(r2, 1.0f);
        out[0] = 7.5f * r0 / tss;   // box
        out[1] = 0.5f * r1 / tss;   // cls
        out[2] = 1.5f * r3 / tss;   // dfl
    }
}

extern "C" void kernel_launch(void* const* d_in, const int* in_sizes, int n_in,
                              void* d_out, int out_size, void* d_ws, size_t ws_size,
                              hipStream_t stream) {
    const float* pred_dist     = (const float*)d_in[0];
    const float* pred_scores   = (const float*)d_in[1];
    const float* anchor_points = (const float*)d_in[2];
    const float* target_bboxes = (const float*)d_in[3];
    const float* target_scores = (const float*)d_in[4];
    const int*   fgmask        = (const int*)d_in[5];

    int nb = (int)(ws_size / (4 * sizeof(float)));
    if (nb > NB_TARGET) nb = NB_TARGET;
    if (nb < 2) nb = 2;
    int fgb = nb / 2;               // 1050 fg blocks at full size (1 chunk/wave)
    if (fgb < 1) fgb = 1;

    float* partials = (float*)d_ws;   // fully overwritten each launch
    loss_main<<<nb, BLOCK, 0, stream>>>(
        pred_dist, pred_scores, anchor_points, target_bboxes, target_scores,
        fgmask, partials, nb, fgb);
    loss_reduce<<<1, BLOCK, 0, stream>>>(partials, nb, (float*)d_out);
}